// Round 16
// baseline (79.405 us; speedup 1.0000x reference)
//
#include <hip/hip_runtime.h>

#define B_   4
#define C_   64
#define H_   128
#define W_   128
#define KS   7
#define G_   4
#define GC_  16
#define KK   49
#define PAD  3
#define TH   8
#define TW   16
#define HW_  (H_ * W_)
#define ZKH  2048              // bytes per kh plane: 128 px * 16 B

typedef float f32x4  __attribute__((ext_vector_type(4)));
typedef short bf16x8 __attribute__((ext_vector_type(8)));
typedef unsigned int u32x4 __attribute__((ext_vector_type(4)));
typedef unsigned int u32x2 __attribute__((ext_vector_type(2)));
typedef __fp16 h16x2 __attribute__((ext_vector_type(2)));   // matches gfx950 builtins

__device__ __forceinline__ unsigned f2bf(float f) {   // RNE float->bf16 (low 16)
    unsigned u = __float_as_uint(f);
    unsigned r = u + 0x7FFFu + ((u >> 16) & 1u);
    return r >> 16;
}
__device__ __forceinline__ unsigned pk2(float a, float b) {  // 2xf32 -> packed f16x2
    union { h16x2 h; unsigned u; } x;
    x.h = __builtin_amdgcn_cvt_pkrtz(a, b);
    return x.u;
}
__device__ __forceinline__ h16x2 ash2(unsigned u) {
    union { unsigned u; h16x2 h; } x; x.u = u; return x.h;
}
__device__ __forceinline__ unsigned short f16b(float f) {
    union { __fp16 h; unsigned short s; } x; x.h = (__fp16)f; return x.s;
}
#if __has_builtin(__builtin_amdgcn_fdot2)
#define DOT2(a, b, c) __builtin_amdgcn_fdot2((a), (b), (c), false)
#else
#define DOT2(a, b, c) ((c) + (float)(a)[0] * (float)(b)[0] + (float)(a)[1] * (float)(b)[1])
#endif

// ======== prep: xT[b][hw][c] bf16, BN-folded bf16 weights, folded bias ======
__global__ __launch_bounds__(256) void prep(
    const float* __restrict__ x,
    const float* __restrict__ cw,
    const float* __restrict__ bng,
    const float* __restrict__ bnb,
    const float* __restrict__ bnm,
    const float* __restrict__ bnv,
    unsigned short* __restrict__ xT,
    unsigned short* __restrict__ cwb,
    float* __restrict__ sb)
{
    const int tid = threadIdx.x;
    const int bid = blockIdx.x;
    if (bid < 1024) {
        __shared__ unsigned short t[64][68];
        const int b   = bid >> 8;
        const int px0 = (bid & 255) * 64;
        const float* xb = x + (size_t)b * C_ * HW_ + px0;
#pragma unroll
        for (int it = 0; it < 16; ++it) {
            const int i = it * 256 + tid;
            const int c = i >> 6, p = i & 63;
            t[p][c] = (unsigned short)f2bf(xb[(size_t)c * HW_ + p]);
        }
        __syncthreads();
        const int p = tid >> 2, q = tid & 3;
        unsigned int o[8];
#pragma unroll
        for (int j = 0; j < 8; ++j)
            o[j] = (unsigned)t[p][q * 16 + 2 * j] | ((unsigned)t[p][q * 16 + 2 * j + 1] << 16);
        unsigned int* dst = (unsigned int*)(xT + ((size_t)(b * HW_ + px0 + p)) * C_ + q * 16);
        u32x4 v0, v1;
        v0[0] = o[0]; v0[1] = o[1]; v0[2] = o[2]; v0[3] = o[3];
        v1[0] = o[4]; v1[1] = o[5]; v1[2] = o[6]; v1[3] = o[7];
        *(u32x4*)dst = v0;
        *(u32x4*)(dst + 4) = v1;
    } else {
        if (tid < 196) {   // folded bias
            const float sc = bng[tid] * rsqrtf(bnv[tid] + 1e-5f);
            sb[tid] = bnb[tid] - bnm[tid] * sc;
        }
        const int g  = tid >> 6;
        const int kp = tid & 63;
        unsigned int* dst = (unsigned int*)(cwb + ((size_t)(g * 64 + kp)) * C_);
        if (kp < KK) {
            const int o = g * KK + kp;
            const float sc = bng[o] * rsqrtf(bnv[o] + 1e-5f);
            const float* wp = cw + (size_t)o * C_;
#pragma unroll
            for (int c = 0; c < C_; c += 2)
                dst[c >> 1] = f2bf(wp[c] * sc) | (f2bf(wp[c + 1] * sc) << 16);
        } else {
#pragma unroll
            for (int c2 = 0; c2 < C_ / 2; ++c2) dst[c2] = 0u;
        }
    }
}

// ======== main: conv (MFMA, precomputed frags) + f16-dot2 involution ========
__global__ __launch_bounds__(256, 4) void invol_mfma11(
    const float* __restrict__ x,
    const unsigned short* __restrict__ xT,
    const unsigned short* __restrict__ cwb,
    const float* __restrict__ sb,
    float* __restrict__ out)
{
    // z layout: [kh][px][8 f16] = kw 0..6 + zero pad  (7*128*16 = 14336 B)
    __shared__ __align__(16) unsigned short z_sh[KS * 128 * 8];
    __shared__ float sbias[KK];

    const int tid  = threadIdx.x;
    const int lane = tid & 63;
    const int wv   = tid >> 6;
    const int l15  = lane & 15;
    const int l4   = lane >> 4;

    // XCD-locality swizzle (r13: FETCH 37->27 MB): bid&7 = XCD, one (b,g-pair)
    // per XCD = 4 MB x footprint = its L2.
    const int bid = blockIdx.x;
    const int xcd = bid & 7;
    const int s   = bid >> 3;
    const int b   = xcd >> 1;
    const int g   = (xcd & 1) * 2 + (s >> 7);
    const int by  = (s >> 3) & 15;
    const int bx  = s & 7;
    const int w0  = bx * TW;
    const int h0  = by * TH;

    if (tid < KK) sbias[tid] = sb[g * KK + tid];

    // ---- A fragments: one dwordx4 each (xT is [hw][c] bf16) ----
    bf16x8 afr[2][2];
    {
        const unsigned short* xTb = xT + (size_t)b * HW_ * C_;
#pragma unroll
        for (int mt = 0; mt < 2; ++mt) {
            const int hh = h0 + wv * 2 + mt;
            const unsigned short* xp = xTb + ((size_t)(hh * W_ + w0 + l15)) * C_;
#pragma unroll
            for (int ks = 0; ks < 2; ++ks)
                afr[mt][ks] = *(const bf16x8*)(xp + ks * 32 + l4 * 8);
        }
    }

    // ---- B fragments (cwb: [g][64k][c] bf16, BN-scale folded) ----
    bf16x8 bfr[4][2];
    {
        const unsigned short* cwg = cwb + (size_t)g * 64 * C_;
#pragma unroll
        for (int nt = 0; nt < 4; ++nt) {
            const int k = nt * 16 + l15;
#pragma unroll
            for (int ks = 0; ks < 2; ++ks)
                bfr[nt][ks] = *(const bf16x8*)(cwg + k * C_ + ks * 32 + l4 * 8);
        }
    }

    __syncthreads();   // sbias visible

    // ---- MFMA: z[px][k] ----
    f32x4 acc1[2][4];
#pragma unroll
    for (int mt = 0; mt < 2; ++mt)
#pragma unroll
        for (int nt = 0; nt < 4; ++nt) {
            f32x4 a = {0.f, 0.f, 0.f, 0.f};
            a = __builtin_amdgcn_mfma_f32_16x16x32_bf16(afr[mt][0], bfr[nt][0], a, 0, 0, 0);
            a = __builtin_amdgcn_mfma_f32_16x16x32_bf16(afr[mt][1], bfr[nt][1], a, 0, 0, 0);
            acc1[mt][nt] = a;
        }

    // ---- epilogue: +bias, SiLU -> f16 -> z_sh[kh][px][kw] (+ pad zeroing) ----
#pragma unroll
    for (int nt = 0; nt < 4; ++nt) {
        const int k = nt * 16 + l15;
        if (k < KK) {
            const int kh = (k * 9363) >> 16;        // k / 7
            const int kw = k - kh * 7;
            const int bofs = kh * ZKH + kw * 2;
            const float bi = sbias[k];
#pragma unroll
            for (int mt = 0; mt < 2; ++mt) {
                const int px0 = (wv * 2 + mt) * 16 + l4 * 4;
#pragma unroll
                for (int r = 0; r < 4; ++r) {
                    const float t = acc1[mt][nt][r] + bi;
                    const float v = __fdividef(t, 1.0f + __expf(-t));
                    *(unsigned short*)((char*)z_sh + bofs + (px0 + r) * 16) = f16b(v);
                }
            }
        } else if (k < 56) {                        // zero the 8th-tap pad
            const int khp = k - KK;
#pragma unroll
            for (int mt = 0; mt < 2; ++mt) {
                const int px0 = (wv * 2 + mt) * 16 + l4 * 4;
#pragma unroll
                for (int r = 0; r < 4; ++r)
                    *(unsigned short*)((char*)z_sh + khp * ZKH + (px0 + r) * 16 + 14) = 0;
            }
        }
    }

    __syncthreads();   // z visible

    // ---- involution: thread = (c2, y8, xh); f16 dot2, 2-deep pipelined kh ----
    const int c2 = tid >> 4;
    const int y8 = (tid >> 1) & 7;
    const int xh = tid & 1;
    const bool ledge = (bx == 0) & (xh == 0);
    const bool redge = (bx == W_ / TW - 1) & (xh == 1);

    float av[8] = {0.f, 0.f, 0.f, 0.f, 0.f, 0.f, 0.f, 0.f};

    const float* xc = x + (size_t)(b * C_ + g * GC_ + c2) * HW_;
    const char* zpx = (const char*)z_sh + (y8 * 16 + xh * 8) * 16;

    auto loadq = [&](f32x4* q, int KH) {            // issue row loads only
        const int gh  = h0 + y8 + KH - PAD;
        const int ghc = gh < 0 ? 0 : (gh > H_ - 1 ? H_ - 1 : gh);
        const float* rp = xc + (size_t)ghc * W_;
        if (ledge) {
            const f32x4* vp = (const f32x4*)rp;
            q[0] = vp[0]; q[1] = vp[1]; q[2] = vp[2];
        } else if (redge) {
            const f32x4* vp = (const f32x4*)(rp + 116);
            q[0] = vp[0]; q[1] = vp[1]; q[2] = vp[2];
        } else {
            const f32x4* vp = (const f32x4*)(rp + w0 + xh * 8 - 4);
            q[0] = vp[0]; q[1] = vp[1]; q[2] = vp[2]; q[3] = vp[3];
        }
    };
    // d[i] = f16 pair (row[2i], row[2i+1]); row[j] = x[w0+xh*8-3 + j] (0 at edges)
    auto packd = [&](unsigned* d, const f32x4* q) {
        if (ledge) {
            d[0] = 0u;
            d[1] = pk2(0.f, q[0][0]);
            d[2] = pk2(q[0][1], q[0][2]); d[3] = pk2(q[0][3], q[1][0]);
            d[4] = pk2(q[1][1], q[1][2]); d[5] = pk2(q[1][3], q[2][0]);
            d[6] = pk2(q[2][1], q[2][2]);
        } else if (redge) {
            d[0] = pk2(q[0][1], q[0][2]); d[1] = pk2(q[0][3], q[1][0]);
            d[2] = pk2(q[1][1], q[1][2]); d[3] = pk2(q[1][3], q[2][0]);
            d[4] = pk2(q[2][1], q[2][2]); d[5] = pk2(q[2][3], 0.f);
            d[6] = 0u;
        } else {
            d[0] = pk2(q[0][1], q[0][2]); d[1] = pk2(q[0][3], q[1][0]);
            d[2] = pk2(q[1][1], q[1][2]); d[3] = pk2(q[1][3], q[2][0]);
            d[4] = pk2(q[2][1], q[2][2]); d[5] = pk2(q[2][3], q[3][0]);
            d[6] = pk2(q[3][1], q[3][2]);
        }
    };
    auto fmad = [&](const unsigned* d, int KH) {
        const int gh = h0 + y8 + KH - PAD;
        if (gh >= 0 && gh < H_) {
            unsigned rO[7];
#pragma unroll
            for (int i = 0; i < 6; ++i)
                rO[i] = __builtin_amdgcn_alignbit(d[i + 1], d[i], 16);
            rO[6] = __builtin_amdgcn_alignbit(d[6], d[6], 16);
            const char* zr = zpx + KH * ZKH;
#pragma unroll
            for (int p = 0; p < 8; ++p) {
                const u32x4 q = *(const u32x4*)(zr + p * 16);  // 4 z-pairs (kw)
                const unsigned* pr = (p & 1) ? &rO[p >> 1] : &d[p >> 1];
                float a = av[p];
                a = DOT2(ash2(q[0]), ash2(pr[0]), a);
                a = DOT2(ash2(q[1]), ash2(pr[1]), a);
                a = DOT2(ash2(q[2]), ash2(pr[2]), a);
                a = DOT2(ash2(q[3]), ash2(pr[3]), a);
                av[p] = a;
            }
        }
    };

    f32x4 qA[4], qB[4];
    unsigned dA[7], dB[7];
    loadq(qA, 0);
#pragma unroll 1
    for (int kh2 = 0; kh2 < 3; ++kh2) {             // kh rolled (r4 spill lesson)
        loadq(qB, 2 * kh2 + 1);
        packd(dA, qA); fmad(dA, 2 * kh2);
        loadq(qA, 2 * kh2 + 2);
        packd(dB, qB); fmad(dB, 2 * kh2 + 1);
    }
    packd(dA, qA); fmad(dA, 6);

    // ---- coalesced stores: 2x float4 ----
    float* og = out + (size_t)(b * C_ + g * GC_ + c2) * HW_
                    + (h0 + y8) * W_ + w0 + xh * 8;
    {
        f32x4 v;
        v[0] = av[0]; v[1] = av[1]; v[2] = av[2]; v[3] = av[3];
        *(f32x4*)(og + 0) = v;
        v[0] = av[4]; v[1] = av[5]; v[2] = av[6]; v[3] = av[7];
        *(f32x4*)(og + 4) = v;
    }
}

extern "C" void kernel_launch(void* const* d_in, const int* in_sizes, int n_in,
                              void* d_out, int out_size, void* d_ws, size_t ws_size,
                              hipStream_t stream) {
    const float* x   = (const float*)d_in[0];
    const float* cw  = (const float*)d_in[1];
    const float* bng = (const float*)d_in[2];
    const float* bnb = (const float*)d_in[3];
    const float* bnm = (const float*)d_in[4];
    const float* bnv = (const float*)d_in[5];
    float* out = (float*)d_out;

    unsigned short* xT  = (unsigned short*)d_ws;                 // 8,388,608 B
    unsigned short* cwb = xT + (size_t)B_ * HW_ * C_;            // 32,768 B
    float*          sbp = (float*)(cwb + (size_t)G_ * 64 * C_);  // 784 B

    prep<<<dim3(1025), dim3(256), 0, stream>>>(x, cw, bng, bnb, bnm, bnv,
                                               xT, cwb, sbp);
    invol_mfma11<<<dim3(2048), dim3(256), 0, stream>>>(x, xT, cwb, sbp, out);
}

// Round 17
// 46.583 us; speedup vs baseline: 1.7046x; 1.7046x over previous
//
#include <hip/hip_runtime.h>

#define B_   4
#define C_   64
#define H_   128
#define W_   128
#define KS   7
#define G_   4
#define GC_  16
#define KK   49
#define PAD  3
#define TH   8
#define TW   16
#define HW_  (H_ * W_)
#define ZKHB 2112              // bytes per kh plane: 128px*16B + 64B bank shift

typedef float f32x4  __attribute__((ext_vector_type(4)));
typedef short bf16x8 __attribute__((ext_vector_type(8)));
typedef unsigned int u32x4 __attribute__((ext_vector_type(4)));
typedef unsigned int u32x2 __attribute__((ext_vector_type(2)));
typedef __fp16 h16x2 __attribute__((ext_vector_type(2)));

__device__ __forceinline__ unsigned f2bf(float f) {
    unsigned u = __float_as_uint(f);
    unsigned r = u + 0x7FFFu + ((u >> 16) & 1u);
    return r >> 16;
}
__device__ __forceinline__ unsigned pk2(float a, float b) {
    union { h16x2 h; unsigned u; } x;
    x.h = __builtin_amdgcn_cvt_pkrtz(a, b);
    return x.u;
}
__device__ __forceinline__ h16x2 ash2(unsigned u) {
    union { unsigned u; h16x2 h; } x; x.u = u; return x.h;
}
__device__ __forceinline__ unsigned short f16b(float f) {
    union { __fp16 h; unsigned short s; } x; x.h = (__fp16)f; return x.s;
}
#if __has_builtin(__builtin_amdgcn_fdot2)
#define DOT2(a, b, c) __builtin_amdgcn_fdot2((a), (b), (c), false)
#else
#define DOT2(a, b, c) ((c) + (float)(a)[0] * (float)(b)[0] + (float)(a)[1] * (float)(b)[1])
#endif
#define AB(a, b) __builtin_amdgcn_alignbit((a), (b), 16)

// ======== prep: xT[b][hw][c] bf16, BN-folded bf16 weights, folded bias ======
__global__ __launch_bounds__(256) void prep(
    const float* __restrict__ x,
    const float* __restrict__ cw,
    const float* __restrict__ bng,
    const float* __restrict__ bnb,
    const float* __restrict__ bnm,
    const float* __restrict__ bnv,
    unsigned short* __restrict__ xT,
    unsigned short* __restrict__ cwb,
    float* __restrict__ sb)
{
    const int tid = threadIdx.x;
    const int bid = blockIdx.x;
    if (bid < 1024) {
        __shared__ unsigned short t[64][68];
        const int b   = bid >> 8;
        const int px0 = (bid & 255) * 64;
        const float* xb = x + (size_t)b * C_ * HW_ + px0;
#pragma unroll
        for (int it = 0; it < 16; ++it) {
            const int i = it * 256 + tid;
            const int c = i >> 6, p = i & 63;
            t[p][c] = (unsigned short)f2bf(xb[(size_t)c * HW_ + p]);
        }
        __syncthreads();
        const int p = tid >> 2, q = tid & 3;
        unsigned int o[8];
#pragma unroll
        for (int j = 0; j < 8; ++j)
            o[j] = (unsigned)t[p][q * 16 + 2 * j] | ((unsigned)t[p][q * 16 + 2 * j + 1] << 16);
        unsigned int* dst = (unsigned int*)(xT + ((size_t)(b * HW_ + px0 + p)) * C_ + q * 16);
        u32x4 v0, v1;
        v0[0] = o[0]; v0[1] = o[1]; v0[2] = o[2]; v0[3] = o[3];
        v1[0] = o[4]; v1[1] = o[5]; v1[2] = o[6]; v1[3] = o[7];
        *(u32x4*)dst = v0;
        *(u32x4*)(dst + 4) = v1;
    } else {
        if (tid < 196) {
            const float sc = bng[tid] * rsqrtf(bnv[tid] + 1e-5f);
            sb[tid] = bnb[tid] - bnm[tid] * sc;
        }
        const int g  = tid >> 6;
        const int kp = tid & 63;
        unsigned int* dst = (unsigned int*)(cwb + ((size_t)(g * 64 + kp)) * C_);
        if (kp < KK) {
            const int o = g * KK + kp;
            const float sc = bng[o] * rsqrtf(bnv[o] + 1e-5f);
            const float* wp = cw + (size_t)o * C_;
#pragma unroll
            for (int c = 0; c < C_; c += 2)
                dst[c >> 1] = f2bf(wp[c] * sc) | (f2bf(wp[c + 1] * sc) << 16);
        } else {
#pragma unroll
            for (int c2 = 0; c2 < C_ / 2; ++c2) dst[c2] = 0u;
        }
    }
}

// ---- involution phase macros: pure named-SSA (r16 lesson: arrays through
// lambdas -> SROA failure -> 130 MB scratch). ----
#define LOADQ(S, KH_) do {                                                     \
    const int gh_  = h0 + y8 + (KH_) - PAD;                                    \
    const int ghc_ = gh_ < 0 ? 0 : (gh_ > H_ - 1 ? H_ - 1 : gh_);              \
    const float* rp_ = xc + (size_t)ghc_ * W_;                                 \
    if (ledge) {                                                               \
        const f32x4* vp_ = (const f32x4*)rp_;                                  \
        q##S##0 = vp_[0]; q##S##1 = vp_[1]; q##S##2 = vp_[2];                  \
    } else if (redge) {                                                        \
        const f32x4* vp_ = (const f32x4*)(rp_ + 116);                          \
        q##S##0 = vp_[0]; q##S##1 = vp_[1]; q##S##2 = vp_[2];                  \
    } else {                                                                   \
        const f32x4* vp_ = (const f32x4*)(rp_ + w0 + xh * 8 - 4);              \
        q##S##0 = vp_[0]; q##S##1 = vp_[1]; q##S##2 = vp_[2]; q##S##3 = vp_[3];\
    }                                                                          \
} while (0)

#define PACKD(S) do {                                                          \
    if (ledge) {                                                               \
        d##S##0 = 0u;                                                          \
        d##S##1 = pk2(0.f, q##S##0[0]);                                        \
        d##S##2 = pk2(q##S##0[1], q##S##0[2]);                                 \
        d##S##3 = pk2(q##S##0[3], q##S##1[0]);                                 \
        d##S##4 = pk2(q##S##1[1], q##S##1[2]);                                 \
        d##S##5 = pk2(q##S##1[3], q##S##2[0]);                                 \
        d##S##6 = pk2(q##S##2[1], q##S##2[2]);                                 \
    } else if (redge) {                                                        \
        d##S##0 = pk2(q##S##0[1], q##S##0[2]);                                 \
        d##S##1 = pk2(q##S##0[3], q##S##1[0]);                                 \
        d##S##2 = pk2(q##S##1[1], q##S##1[2]);                                 \
        d##S##3 = pk2(q##S##1[3], q##S##2[0]);                                 \
        d##S##4 = pk2(q##S##2[1], q##S##2[2]);                                 \
        d##S##5 = pk2(q##S##2[3], 0.f);                                        \
        d##S##6 = 0u;                                                          \
    } else {                                                                   \
        d##S##0 = pk2(q##S##0[1], q##S##0[2]);                                 \
        d##S##1 = pk2(q##S##0[3], q##S##1[0]);                                 \
        d##S##2 = pk2(q##S##1[1], q##S##1[2]);                                 \
        d##S##3 = pk2(q##S##1[3], q##S##2[0]);                                 \
        d##S##4 = pk2(q##S##2[1], q##S##2[2]);                                 \
        d##S##5 = pk2(q##S##2[3], q##S##3[0]);                                 \
        d##S##6 = pk2(q##S##3[1], q##S##3[2]);                                 \
    }                                                                          \
} while (0)

#define FMAD(S, KH_) do {                                                      \
    const int gh_ = h0 + y8 + (KH_) - PAD;                                     \
    if (gh_ >= 0 && gh_ < H_) {                                                \
        const int zo_ = (KH_) * ZKHB;                                          \
        const unsigned r0_ = AB(d##S##1, d##S##0);                             \
        const unsigned r1_ = AB(d##S##2, d##S##1);                             \
        const unsigned r2_ = AB(d##S##3, d##S##2);                             \
        const unsigned r3_ = AB(d##S##4, d##S##3);                             \
        const unsigned r4_ = AB(d##S##5, d##S##4);                             \
        const unsigned r5_ = AB(d##S##6, d##S##5);                             \
        const unsigned r6_ = AB(d##S##6, d##S##6);                             \
        u32x4 q_;                                                              \
        q_ = *(const u32x4*)(zp0 + zo_);                                       \
        a0 = DOT2(ash2(q_[0]), ash2(d##S##0), a0);                             \
        a0 = DOT2(ash2(q_[1]), ash2(d##S##1), a0);                             \
        a0 = DOT2(ash2(q_[2]), ash2(d##S##2), a0);                             \
        a0 = DOT2(ash2(q_[3]), ash2(d##S##3), a0);                             \
        q_ = *(const u32x4*)(zp1 + zo_);                                       \
        a1 = DOT2(ash2(q_[0]), ash2(r0_), a1);                                 \
        a1 = DOT2(ash2(q_[1]), ash2(r1_), a1);                                 \
        a1 = DOT2(ash2(q_[2]), ash2(r2_), a1);                                 \
        a1 = DOT2(ash2(q_[3]), ash2(r3_), a1);                                 \
        q_ = *(const u32x4*)(zp2 + zo_);                                       \
        a2 = DOT2(ash2(q_[0]), ash2(d##S##1), a2);                             \
        a2 = DOT2(ash2(q_[1]), ash2(d##S##2), a2);                             \
        a2 = DOT2(ash2(q_[2]), ash2(d##S##3), a2);                             \
        a2 = DOT2(ash2(q_[3]), ash2(d##S##4), a2);                             \
        q_ = *(const u32x4*)(zp3 + zo_);                                       \
        a3 = DOT2(ash2(q_[0]), ash2(r1_), a3);                                 \
        a3 = DOT2(ash2(q_[1]), ash2(r2_), a3);                                 \
        a3 = DOT2(ash2(q_[2]), ash2(r3_), a3);                                 \
        a3 = DOT2(ash2(q_[3]), ash2(r4_), a3);                                 \
        q_ = *(const u32x4*)(zp4 + zo_);                                       \
        a4 = DOT2(ash2(q_[0]), ash2(d##S##2), a4);                             \
        a4 = DOT2(ash2(q_[1]), ash2(d##S##3), a4);                             \
        a4 = DOT2(ash2(q_[2]), ash2(d##S##4), a4);                             \
        a4 = DOT2(ash2(q_[3]), ash2(d##S##5), a4);                             \
        q_ = *(const u32x4*)(zp5 + zo_);                                       \
        a5 = DOT2(ash2(q_[0]), ash2(r2_), a5);                                 \
        a5 = DOT2(ash2(q_[1]), ash2(r3_), a5);                                 \
        a5 = DOT2(ash2(q_[2]), ash2(r4_), a5);                                 \
        a5 = DOT2(ash2(q_[3]), ash2(r5_), a5);                                 \
        q_ = *(const u32x4*)(zp6 + zo_);                                       \
        a6 = DOT2(ash2(q_[0]), ash2(d##S##3), a6);                             \
        a6 = DOT2(ash2(q_[1]), ash2(d##S##4), a6);                             \
        a6 = DOT2(ash2(q_[2]), ash2(d##S##5), a6);                             \
        a6 = DOT2(ash2(q_[3]), ash2(d##S##6), a6);                             \
        q_ = *(const u32x4*)(zp7 + zo_);                                       \
        a7 = DOT2(ash2(q_[0]), ash2(r3_), a7);                                 \
        a7 = DOT2(ash2(q_[1]), ash2(r4_), a7);                                 \
        a7 = DOT2(ash2(q_[2]), ash2(r5_), a7);                                 \
        a7 = DOT2(ash2(q_[3]), ash2(r6_), a7);                                 \
    }                                                                          \
} while (0)

// ======== main: conv (MFMA, precomputed frags) + f16-dot2 involution ========
__global__ __launch_bounds__(256, 4) void invol_mfma12(
    const float* __restrict__ x,
    const unsigned short* __restrict__ xT,
    const unsigned short* __restrict__ cwb,
    const float* __restrict__ sb,
    float* __restrict__ out)
{
    // z layout: addr = kh*2112 + (px*16 ^ ((px>>3&7)<<4)) + kw*2  (f16)
    __shared__ __align__(16) char z_sh[KS * ZKHB];   // 14784 B
    __shared__ float sbias[KK];

    const int tid  = threadIdx.x;
    const int lane = tid & 63;
    const int wv   = tid >> 6;
    const int l15  = lane & 15;
    const int l4   = lane >> 4;

    // XCD-locality swizzle (r13: FETCH 37->27 MB)
    const int bid = blockIdx.x;
    const int xcd = bid & 7;
    const int s   = bid >> 3;
    const int b   = xcd >> 1;
    const int g   = (xcd & 1) * 2 + (s >> 7);
    const int by  = (s >> 3) & 15;
    const int bx  = s & 7;
    const int w0  = bx * TW;
    const int h0  = by * TH;

    if (tid < KK) sbias[tid] = sb[g * KK + tid];

    // ---- A fragments (xT: [hw][c] bf16) ----
    bf16x8 afr[2][2];
    {
        const unsigned short* xTb = xT + (size_t)b * HW_ * C_;
#pragma unroll
        for (int mt = 0; mt < 2; ++mt) {
            const int hh = h0 + wv * 2 + mt;
            const unsigned short* xp = xTb + ((size_t)(hh * W_ + w0 + l15)) * C_;
#pragma unroll
            for (int ks = 0; ks < 2; ++ks)
                afr[mt][ks] = *(const bf16x8*)(xp + ks * 32 + l4 * 8);
        }
    }

    // ---- B fragments (cwb: [g][64k][c] bf16, BN-scale folded) ----
    bf16x8 bfr[4][2];
    {
        const unsigned short* cwg = cwb + (size_t)g * 64 * C_;
#pragma unroll
        for (int nt = 0; nt < 4; ++nt) {
            const int k = nt * 16 + l15;
#pragma unroll
            for (int ks = 0; ks < 2; ++ks)
                bfr[nt][ks] = *(const bf16x8*)(cwg + k * C_ + ks * 32 + l4 * 8);
        }
    }

    __syncthreads();

    // ---- MFMA: z[px][k] ----
    f32x4 acc1[2][4];
#pragma unroll
    for (int mt = 0; mt < 2; ++mt)
#pragma unroll
        for (int nt = 0; nt < 4; ++nt) {
            f32x4 a = {0.f, 0.f, 0.f, 0.f};
            a = __builtin_amdgcn_mfma_f32_16x16x32_bf16(afr[mt][0], bfr[nt][0], a, 0, 0, 0);
            a = __builtin_amdgcn_mfma_f32_16x16x32_bf16(afr[mt][1], bfr[nt][1], a, 0, 0, 0);
            acc1[mt][nt] = a;
        }

    // ---- epilogue: +bias, SiLU -> f16 -> swizzled z (+ 8th-tap pad zero) ----
#pragma unroll
    for (int nt = 0; nt < 4; ++nt) {
        const int k = nt * 16 + l15;
        if (k < KK) {
            const int kh = (k * 9363) >> 16;        // k/7
            const int kw = k - kh * 7;
            const int kbase = kh * ZKHB + kw * 2;
            const float bi = sbias[k];
#pragma unroll
            for (int mt = 0; mt < 2; ++mt) {
                const int px0 = (wv * 2 + mt) * 16 + l4 * 4;
#pragma unroll
                for (int r = 0; r < 4; ++r) {
                    const int px = px0 + r;
                    const int sw = (px << 4) ^ (((px >> 3) & 7) << 4);
                    const float t = acc1[mt][nt][r] + bi;
                    const float v = __fdividef(t, 1.0f + __expf(-t));
                    *(unsigned short*)(z_sh + kbase + sw) = f16b(v);
                }
            }
        } else if (k < 56) {
            const int khp = k - KK;
#pragma unroll
            for (int mt = 0; mt < 2; ++mt) {
                const int px0 = (wv * 2 + mt) * 16 + l4 * 4;
#pragma unroll
                for (int r = 0; r < 4; ++r) {
                    const int px = px0 + r;
                    const int sw = (px << 4) ^ (((px >> 3) & 7) << 4);
                    *(unsigned short*)(z_sh + khp * ZKHB + sw + 14) = 0;
                }
            }
        }
    }

    __syncthreads();

    // ---- involution: thread = (c2, y8, xh); f16 dot2, 2-deep pipeline ----
    const int c2 = tid >> 4;
    const int y8 = (tid >> 1) & 7;
    const int xh = tid & 1;
    const bool ledge = (bx == 0) & (xh == 0);
    const bool redge = (bx == W_ / TW - 1) & (xh == 1);

    float a0 = 0.f, a1 = 0.f, a2 = 0.f, a3 = 0.f;
    float a4 = 0.f, a5 = 0.f, a6 = 0.f, a7 = 0.f;

    const float* xc = x + (size_t)(b * C_ + g * GC_ + c2) * HW_;

    // 8 swizzled z base pointers (one per output pixel), kh via +zo_ offset
    const int pxb = y8 * 16 + xh * 8;
    const int mx  = ((2 * y8 + xh) & 7) << 4;
    const char* zbase = z_sh + (pxb << 4);
    const char* zp0 = zbase + ((0 << 4) ^ mx);
    const char* zp1 = zbase + ((1 << 4) ^ mx);
    const char* zp2 = zbase + ((2 << 4) ^ mx);
    const char* zp3 = zbase + ((3 << 4) ^ mx);
    const char* zp4 = zbase + ((4 << 4) ^ mx);
    const char* zp5 = zbase + ((5 << 4) ^ mx);
    const char* zp6 = zbase + ((6 << 4) ^ mx);
    const char* zp7 = zbase + ((7 << 4) ^ mx);

    f32x4 qA0 = {0,0,0,0}, qA1 = {0,0,0,0}, qA2 = {0,0,0,0}, qA3 = {0,0,0,0};
    f32x4 qB0 = {0,0,0,0}, qB1 = {0,0,0,0}, qB2 = {0,0,0,0}, qB3 = {0,0,0,0};
    unsigned dA0, dA1, dA2, dA3, dA4, dA5, dA6;
    unsigned dB0, dB1, dB2, dB3, dB4, dB5, dB6;

    LOADQ(A, 0);
#pragma unroll 1
    for (int kh2 = 0; kh2 < 3; ++kh2) {             // kh rolled (r4 spill lesson)
        LOADQ(B, 2 * kh2 + 1);
        PACKD(A); FMAD(A, 2 * kh2);
        LOADQ(A, 2 * kh2 + 2);
        PACKD(B); FMAD(B, 2 * kh2 + 1);
    }
    PACKD(A); FMAD(A, 6);

    // ---- coalesced stores: 2x float4 ----
    float* og = out + (size_t)(b * C_ + g * GC_ + c2) * HW_
                    + (h0 + y8) * W_ + w0 + xh * 8;
    {
        f32x4 v;
        v[0] = a0; v[1] = a1; v[2] = a2; v[3] = a3;
        *(f32x4*)(og + 0) = v;
        v[0] = a4; v[1] = a5; v[2] = a6; v[3] = a7;
        *(f32x4*)(og + 4) = v;
    }
}

extern "C" void kernel_launch(void* const* d_in, const int* in_sizes, int n_in,
                              void* d_out, int out_size, void* d_ws, size_t ws_size,
                              hipStream_t stream) {
    const float* x   = (const float*)d_in[0];
    const float* cw  = (const float*)d_in[1];
    const float* bng = (const float*)d_in[2];
    const float* bnb = (const float*)d_in[3];
    const float* bnm = (const float*)d_in[4];
    const float* bnv = (const float*)d_in[5];
    float* out = (float*)d_out;

    unsigned short* xT  = (unsigned short*)d_ws;                 // 8,388,608 B
    unsigned short* cwb = xT + (size_t)B_ * HW_ * C_;            // 32,768 B
    float*          sbp = (float*)(cwb + (size_t)G_ * 64 * C_);  // 784 B

    prep<<<dim3(1025), dim3(256), 0, stream>>>(x, cw, bng, bnb, bnm, bnv,
                                               xT, cwb, sbp);
    invol_mfma12<<<dim3(2048), dim3(256), 0, stream>>>(x, xT, cwb, sbp, out);
}